// Round 3
// baseline (204.442 us; speedup 1.0000x reference)
//
#include <hip/hip_runtime.h>

// Problem constants
#define BQ   2
#define SQ   2048
#define DIMQ 1024
#define HQ   16
#define HDQ  64
#define KQ   64
#define QKV_STRIDE (3 * DIMQ)

typedef __attribute__((ext_vector_type(8))) short short8;   // 8 bf16 (4 VGPRs)
typedef __attribute__((ext_vector_type(4))) float floatx4;  // 4 fp32 acc

typedef const __attribute__((address_space(1))) unsigned short* gas_t;
typedef __attribute__((address_space(3))) unsigned short* las_t;

__device__ __forceinline__ unsigned short f2b(float f) {
    union { float f; unsigned int u; } x; x.f = f;
    unsigned int r = x.u + 0x7fffu + ((x.u >> 16) & 1u);   // RNE
    return (unsigned short)(r >> 16);
}
__device__ __forceinline__ float b2f(unsigned short u) {
    union { unsigned int u; float f; } x; x.u = ((unsigned int)u) << 16;
    return x.f;
}

// ---------------------------------------------------------------------------
// Fused fp32 -> bf16 cast over three buffers (x, w_qkv, w_out), float4 lanes.
__global__ __launch_bounds__(256) void cast3_f32_bf16(const float* __restrict__ s0, unsigned short* __restrict__ d0, int n0,
                                                      const float* __restrict__ s1, unsigned short* __restrict__ d1, int n1,
                                                      const float* __restrict__ s2, unsigned short* __restrict__ d2, int n2) {
    int i = blockIdx.x * blockDim.x + threadIdx.x;
    const float* s; unsigned short* d;
    if (i < n0)                { s = s0; d = d0; }
    else if (i < n0 + n1)      { s = s1; d = d1; i -= n0; }
    else if (i < n0 + n1 + n2) { s = s2; d = d2; i -= n0 + n1; }
    else return;
    float4 v = ((const float4*)s)[i];
    ushort4 o;
    o.x = f2b(v.x); o.y = f2b(v.y); o.z = f2b(v.z); o.w = f2b(v.w);
    ((ushort4*)d)[i] = o;
}

// ---------------------------------------------------------------------------
// C[M,N] = A[M,K] @ B[N,K]^T + bias[N]   (A,B bf16 row-major; C fp32 or bf16)
// BMxBN tile, BK=64 (32 MFMAs between barriers), 256 threads = 4 waves
// (2x2 of BM/2 x BN/2), 16x16x32 MFMA. XOR k-chunk swizzle on the global side.
template <int BM, int BN, typename CT>
__global__ __launch_bounds__(256) void gemm_bf16_nt(const unsigned short* __restrict__ A,
                                                    const unsigned short* __restrict__ B,
                                                    const float* __restrict__ bias,
                                                    CT* __restrict__ C,
                                                    int M, int N, int K) {
    constexpr int MI = BM / 32;          // 16-row mfma tiles per wave
    constexpr int NJ = BN / 32;          // 16-col mfma tiles per wave
    __shared__ unsigned short As[BM * 64];
    __shared__ unsigned short Bs[BN * 64];

    const int tid  = threadIdx.x;
    const int lane = tid & 63;
    const int wv   = tid >> 6;            // 0..3
    const int wm   = (wv >> 1) * (BM / 2);
    const int wn   = (wv & 1) * (BN / 2);
    const int fr   = lane & 15;           // fragment row (m or n)
    const int fq   = lane >> 4;           // quad -> k segment (8 elems)

    const int m0 = blockIdx.y * BM;
    const int n0 = blockIdx.x * BN;

    floatx4 acc[MI][NJ];
#pragma unroll
    for (int i = 0; i < MI; ++i)
#pragma unroll
        for (int j = 0; j < NJ; ++j) acc[i][j] = (floatx4)(0.f);

    const unsigned short* Ab = A + (size_t)m0 * K;
    const unsigned short* Bb = B + (size_t)n0 * K;

    for (int k0 = 0; k0 < K; k0 += 64) {
#pragma unroll
        for (int c = 0; c < (BM + BN) * 8; c += 256) {
            const int cc = c + tid;
            if (cc < BM * 8) {
                const int row = cc >> 3;
                const int kc  = ((cc & 7) ^ (row & 7)) << 3;
                __builtin_amdgcn_global_load_lds(
                    (gas_t)(Ab + (size_t)row * K + k0 + kc),
                    (las_t)&As[cc * 8], 16, 0, 0);
            } else {
                const int c2  = cc - BM * 8;
                const int row = c2 >> 3;
                const int kc  = ((c2 & 7) ^ (row & 7)) << 3;
                __builtin_amdgcn_global_load_lds(
                    (gas_t)(Bb + (size_t)row * K + k0 + kc),
                    (las_t)&Bs[c2 * 8], 16, 0, 0);
            }
        }
        __syncthreads();

#pragma unroll
        for (int ks = 0; ks < 2; ++ks) {
            short8 af[MI], bf[NJ];
#pragma unroll
            for (int i = 0; i < MI; ++i) {
                const int row = wm + i * 16 + fr;
                const int pos = (ks * 4 + fq) ^ (row & 7);
                af[i] = *(const short8*)&As[row * 64 + pos * 8];
            }
#pragma unroll
            for (int j = 0; j < NJ; ++j) {
                const int row = wn + j * 16 + fr;
                const int pos = (ks * 4 + fq) ^ (row & 7);
                bf[j] = *(const short8*)&Bs[row * 64 + pos * 8];
            }
#pragma unroll
            for (int i = 0; i < MI; ++i)
#pragma unroll
                for (int j = 0; j < NJ; ++j)
                    acc[i][j] = __builtin_amdgcn_mfma_f32_16x16x32_bf16(af[i], bf[j], acc[i][j], 0, 0, 0);
        }
        __syncthreads();
    }

    // Epilogue. D mapping: col = lane&15 (=fr), row = (lane>>4)*4 + reg (=fq*4+r)
    float bv[NJ];
#pragma unroll
    for (int j = 0; j < NJ; ++j) bv[j] = bias[n0 + wn + j * 16 + fr];
#pragma unroll
    for (int i = 0; i < MI; ++i) {
#pragma unroll
        for (int r = 0; r < 4; ++r) {
            const size_t row = (size_t)(m0 + wm + i * 16 + fq * 4 + r);
#pragma unroll
            for (int j = 0; j < NJ; ++j) {
                const float v = acc[i][j][r] + bv[j];
                if constexpr (sizeof(CT) == 2)
                    C[row * N + n0 + wn + j * 16 + fr] = (CT)f2b(v);
                else
                    C[row * N + n0 + wn + j * 16 + fr] = (CT)v;
            }
        }
    }
}

// ---------------------------------------------------------------------------
// R7 attention: two-pass softmax + async wave-private LDS staging.
// K/V gathers go through global_load_lds (16B/lane, 1KB/instr) into a
// wave-private double-buffered LDS region: 2 chunks x 4 j-rows in flight per
// wave (8 outstanding DMAs) with hand-counted s_waitcnt vmcnt(4) -- never 0
// mid-loop.  No __syncthreads in the j-loop (buffers are wave-private).
// V chunks 0/1 are issued before the softmax so their latency hides under it.
// Thread t: j-group g = t>>7 (j = 2*jj+g), head h = (t&127)>>3, d0=(t&7)*8.
// qkv: bf16 [B, S, 3, H, HD]. out: bf16 [B, S, H*HD].
__global__ __launch_bounds__(256) void attn_kernel(const unsigned short* __restrict__ qkv,
                                                   const int* __restrict__ routes,
                                                   unsigned short* __restrict__ out) {
    __shared__ int   r_s[KQ];
    __shared__ float m_s[128], l_s[128];
    __shared__ float o_part[8][128];
    // [wave][dbuf][j-in-chunk][64 lanes * 8 shorts] = 32 KB
    __shared__ __align__(16) unsigned short stage[4][2][4][512];

    const int t  = threadIdx.x;           // 0..255
    const int id = blockIdx.x;
    // XCD-contiguity swizzle: same XCD (id%8) gets a contiguous bq range.
    const int bq = (id & 7) * 512 + (id >> 3);
    const int b  = bq >> 11;
    const int q  = bq & 2047;

    if (t < KQ) r_s[t] = routes[q * KQ + t];

    const int g    = t >> 7;              // j-group: 0 or 1
    const int th   = t & 127;
    const int h    = th >> 3;             // head
    const int d0   = (t & 7) * 8;         // dim offset within head
    const int wave = t >> 6;              // 0..3 (g == wave>>1)
    const int lane = t & 63;

    // SCALE * log2(e) folded into q so scores are directly in exp2 domain.
    float qf[8];
    {
        const short8 q8 = *(const short8*)&qkv[((size_t)bq * 3) * DIMQ + h * HDQ + d0];
#pragma unroll
        for (int e = 0; e < 8; ++e) qf[e] = b2f((unsigned short)q8[e]) * 0.18033688011112042f;
    }
    __syncthreads();

    const unsigned short* baseK = qkv + ((size_t)b * SQ * 3 + 1) * DIMQ + h * HDQ + d0;
    const unsigned short* baseV = qkv + ((size_t)b * SQ * 3 + 2) * DIMQ + h * HDQ + d0;

#define ISSUE(base, c, bf) do {                                               \
    _Pragma("unroll")                                                         \
    for (int u = 0; u < 4; ++u) {                                             \
        const size_t roff = (size_t)r_s[((c) * 4 + u) * 2 + g] * QKV_STRIDE;  \
        __builtin_amdgcn_global_load_lds((gas_t)((base) + roff),              \
            (las_t)&stage[wave][bf][u][lane * 8], 16, 0, 0);                  \
    }                                                                         \
} while (0)

#define WAIT4 asm volatile("s_waitcnt vmcnt(4)" ::: "memory")
#define WAIT0 asm volatile("s_waitcnt vmcnt(0)" ::: "memory")

#define COMP_K(c, bf) do {                                                    \
    _Pragma("unroll")                                                         \
    for (int u = 0; u < 4; ++u) {                                             \
        const short8 k8 = *(const short8*)&stage[wave][bf][u][lane * 8];      \
        float p = 0.f;                                                        \
        _Pragma("unroll")                                                     \
        for (int e = 0; e < 8; ++e) p += qf[e] * b2f((unsigned short)k8[e]);  \
        p += __shfl_xor(p, 1, 64);                                            \
        p += __shfl_xor(p, 2, 64);                                            \
        p += __shfl_xor(p, 4, 64);                                            \
        s[(c) * 4 + u] = p;                                                   \
    }                                                                         \
} while (0)

#define COMP_V(c, bf) do {                                                    \
    _Pragma("unroll")                                                         \
    for (int u = 0; u < 4; ++u) {                                             \
        const short8 v8 = *(const short8*)&stage[wave][bf][u][lane * 8];      \
        const float p = s[(c) * 4 + u];                                       \
        _Pragma("unroll")                                                     \
        for (int e = 0; e < 8; ++e) o[e] += p * b2f((unsigned short)v8[e]);   \
    }                                                                         \
} while (0)

    // ---- Pass 1: scores (async LDS-staged K, 2-chunk rotation, 8 in flight)
    float s[32];
    ISSUE(baseK, 0, 0); ISSUE(baseK, 1, 1);
    WAIT4; COMP_K(0, 0); ISSUE(baseK, 2, 0);
    WAIT4; COMP_K(1, 1); ISSUE(baseK, 3, 1);
    WAIT4; COMP_K(2, 0); ISSUE(baseK, 4, 0);
    WAIT4; COMP_K(3, 1); ISSUE(baseK, 5, 1);
    WAIT4; COMP_K(4, 0); ISSUE(baseK, 6, 0);
    WAIT4; COMP_K(5, 1); ISSUE(baseK, 7, 1);
    WAIT4; COMP_K(6, 0); ISSUE(baseV, 0, 0);   // start V staging under softmax
    WAIT4; COMP_K(7, 1); ISSUE(baseV, 1, 1);

    // ---- Pass 2: softmax entirely in registers (tree max, exp2, tree sum)
    float mx[16];
#pragma unroll
    for (int i = 0; i < 16; ++i) mx[i] = fmaxf(s[i], s[i + 16]);
#pragma unroll
    for (int i = 0; i < 8; ++i) mx[i] = fmaxf(mx[i], mx[i + 8]);
#pragma unroll
    for (int i = 0; i < 4; ++i) mx[i] = fmaxf(mx[i], mx[i + 4]);
    const float m = fmaxf(fmaxf(mx[0], mx[1]), fmaxf(mx[2], mx[3]));

    float l0 = 0.f, l1 = 0.f, l2 = 0.f, l3 = 0.f;
#pragma unroll
    for (int jj = 0; jj < 32; jj += 4) {
        s[jj + 0] = exp2f(s[jj + 0] - m); l0 += s[jj + 0];
        s[jj + 1] = exp2f(s[jj + 1] - m); l1 += s[jj + 1];
        s[jj + 2] = exp2f(s[jj + 2] - m); l2 += s[jj + 2];
        s[jj + 3] = exp2f(s[jj + 3] - m); l3 += s[jj + 3];
    }
    const float l = (l0 + l1) + (l2 + l3);

    // ---- Pass 3: PV accumulation (async LDS-staged V, same rotation)
    float o[8];
#pragma unroll
    for (int e = 0; e < 8; ++e) o[e] = 0.f;
    WAIT4; COMP_V(0, 0); ISSUE(baseV, 2, 0);
    WAIT4; COMP_V(1, 1); ISSUE(baseV, 3, 1);
    WAIT4; COMP_V(2, 0); ISSUE(baseV, 4, 0);
    WAIT4; COMP_V(3, 1); ISSUE(baseV, 5, 1);
    WAIT4; COMP_V(4, 0); ISSUE(baseV, 6, 0);
    WAIT4; COMP_V(5, 1); ISSUE(baseV, 7, 1);
    WAIT4; COMP_V(6, 0);
    WAIT0; COMP_V(7, 1);

#undef ISSUE
#undef WAIT4
#undef WAIT0
#undef COMP_K
#undef COMP_V

    // ---- Merge the two j-groups (softmax state merge, exp2 domain), store.
    if (g == 1) {
        m_s[th] = m; l_s[th] = l;
#pragma unroll
        for (int e = 0; e < 8; ++e) o_part[e][th] = o[e];
    }
    __syncthreads();
    if (g == 0) {
        const float m1 = m_s[th], l1m = l_s[th];
        const float mm = fmaxf(m, m1);
        const float a0 = exp2f(m - mm);
        const float a1 = exp2f(m1 - mm);
        const float inv = 1.0f / (l * a0 + l1m * a1);
        float oo[8];
#pragma unroll
        for (int e = 0; e < 8; ++e) oo[e] = (o[e] * a0 + o_part[e][th] * a1) * inv;
        ushort4 lo, hi;
        lo.x = f2b(oo[0]); lo.y = f2b(oo[1]); lo.z = f2b(oo[2]); lo.w = f2b(oo[3]);
        hi.x = f2b(oo[4]); hi.y = f2b(oo[5]); hi.z = f2b(oo[6]); hi.w = f2b(oo[7]);
        ushort4* dst = (ushort4*)&out[(size_t)bq * DIMQ + h * HDQ + d0];
        dst[0] = lo; dst[1] = hi;
    }
}

// ---------------------------------------------------------------------------
extern "C" void kernel_launch(void* const* d_in, const int* in_sizes, int n_in,
                              void* d_out, int out_size, void* d_ws, size_t ws_size,
                              hipStream_t stream) {
    const float* x      = (const float*)d_in[0];
    const float* w_qkv  = (const float*)d_in[1];
    const float* b_qkv  = (const float*)d_in[2];
    const float* w_out  = (const float*)d_in[3];
    const float* b_out  = (const float*)d_in[4];
    const int*   routes = (const int*)d_in[5];
    float* out = (float*)d_out;

    // ws layout (bytes): [0,24M) qkv bf16 | [24M,..) xb / attnb (aliased)
    //                    then w_qkv_bf16, w_out_bf16
    char* ws = (char*)d_ws;
    unsigned short* qkvb  = (unsigned short*)ws;                      // 24 MB
    unsigned short* xb    = (unsigned short*)(ws + 25165824);         // 8.4 MB
    unsigned short* attnb = xb;                                       // aliased
    unsigned short* wqb   = (unsigned short*)(ws + 33554432);         // 6.3 MB
    unsigned short* wob   = (unsigned short*)(ws + 39845888);         // 2.1 MB

    const int M = BQ * SQ;   // 4096
    dim3 blk(256);

    // Fused casts (x, w_qkv, w_out), float4 per thread
    {
        const int n0 = M * DIMQ / 4, n1 = 3 * DIMQ * DIMQ / 4, n2 = DIMQ * DIMQ / 4;
        cast3_f32_bf16<<<(n0 + n1 + n2 + 255) / 256, blk, 0, stream>>>(
            x, xb, n0, w_qkv, wqb, n1, w_out, wob, n2);
    }

    // 1) QKV projection -> bf16 qkv [B,S,3,H,HD]  (BK=64, 32 MFMAs/barrier)
    gemm_bf16_nt<128, 128, unsigned short><<<dim3(3 * DIMQ / 128, M / 128), blk, 0, stream>>>(
        xb, wqb, b_qkv, qkvb, M, 3 * DIMQ, DIMQ);

    // 2) Routed attention: two-pass softmax + async LDS-staged gathers
    attn_kernel<<<BQ * SQ, blk, 0, stream>>>(qkvb, routes, attnb);

    // 3) Output projection -> fp32 final output (128x64 tiles: 512 blocks)
    gemm_bf16_nt<128, 64, float><<<dim3(DIMQ / 64, M / 128), blk, 0, stream>>>(
        attnb, wob, b_out, out, M, DIMQ, DIMQ);
}

// Round 5
// 186.015 us; speedup vs baseline: 1.0991x; 1.0991x over previous
//
#include <hip/hip_runtime.h>

// Problem constants
#define BQ   2
#define SQ   2048
#define DIMQ 1024
#define HQ   16
#define HDQ  64
#define KQ   64
#define QKV_STRIDE (3 * DIMQ)

typedef __attribute__((ext_vector_type(8))) short short8;   // 8 bf16 (4 VGPRs)
typedef __attribute__((ext_vector_type(4))) float floatx4;  // 4 fp32 acc

typedef const __attribute__((address_space(1))) unsigned short* gas_t;
typedef __attribute__((address_space(3))) unsigned short* las_t;

__device__ __forceinline__ unsigned short f2b(float f) {
    union { float f; unsigned int u; } x; x.f = f;
    unsigned int r = x.u + 0x7fffu + ((x.u >> 16) & 1u);   // RNE
    return (unsigned short)(r >> 16);
}
__device__ __forceinline__ float b2f(unsigned short u) {
    union { unsigned int u; float f; } x; x.u = ((unsigned int)u) << 16;
    return x.f;
}

// ---------------------------------------------------------------------------
// Fused fp32 -> bf16 cast over three buffers (x, w_qkv, w_out), float4 lanes.
__global__ __launch_bounds__(256) void cast3_f32_bf16(const float* __restrict__ s0, unsigned short* __restrict__ d0, int n0,
                                                      const float* __restrict__ s1, unsigned short* __restrict__ d1, int n1,
                                                      const float* __restrict__ s2, unsigned short* __restrict__ d2, int n2) {
    int i = blockIdx.x * blockDim.x + threadIdx.x;
    const float* s; unsigned short* d;
    if (i < n0)                { s = s0; d = d0; }
    else if (i < n0 + n1)      { s = s1; d = d1; i -= n0; }
    else if (i < n0 + n1 + n2) { s = s2; d = d2; i -= n0 + n1; }
    else return;
    float4 v = ((const float4*)s)[i];
    ushort4 o;
    o.x = f2b(v.x); o.y = f2b(v.y); o.z = f2b(v.z); o.w = f2b(v.w);
    ((ushort4*)d)[i] = o;
}

// ---------------------------------------------------------------------------
// C[M,N] = A[M,K] @ B[N,K]^T + bias[N]   (A,B bf16 row-major; C fp32 or bf16)
// BMxBN tile, BK=64 (32 MFMAs between barriers), 256 threads = 4 waves
// (2x2 of BM/2 x BN/2), 16x16x32 MFMA. XOR k-chunk swizzle on the global side.
template <int BM, int BN, typename CT>
__global__ __launch_bounds__(256) void gemm_bf16_nt(const unsigned short* __restrict__ A,
                                                    const unsigned short* __restrict__ B,
                                                    const float* __restrict__ bias,
                                                    CT* __restrict__ C,
                                                    int M, int N, int K) {
    constexpr int MI = BM / 32;          // 16-row mfma tiles per wave
    constexpr int NJ = BN / 32;          // 16-col mfma tiles per wave
    __shared__ unsigned short As[BM * 64];
    __shared__ unsigned short Bs[BN * 64];

    const int tid  = threadIdx.x;
    const int lane = tid & 63;
    const int wv   = tid >> 6;            // 0..3
    const int wm   = (wv >> 1) * (BM / 2);
    const int wn   = (wv & 1) * (BN / 2);
    const int fr   = lane & 15;           // fragment row (m or n)
    const int fq   = lane >> 4;           // quad -> k segment (8 elems)

    const int m0 = blockIdx.y * BM;
    const int n0 = blockIdx.x * BN;

    floatx4 acc[MI][NJ];
#pragma unroll
    for (int i = 0; i < MI; ++i)
#pragma unroll
        for (int j = 0; j < NJ; ++j) acc[i][j] = (floatx4)(0.f);

    const unsigned short* Ab = A + (size_t)m0 * K;
    const unsigned short* Bb = B + (size_t)n0 * K;

    for (int k0 = 0; k0 < K; k0 += 64) {
#pragma unroll
        for (int c = 0; c < (BM + BN) * 8; c += 256) {
            const int cc = c + tid;
            if (cc < BM * 8) {
                const int row = cc >> 3;
                const int kc  = ((cc & 7) ^ (row & 7)) << 3;
                __builtin_amdgcn_global_load_lds(
                    (gas_t)(Ab + (size_t)row * K + k0 + kc),
                    (las_t)&As[cc * 8], 16, 0, 0);
            } else {
                const int c2  = cc - BM * 8;
                const int row = c2 >> 3;
                const int kc  = ((c2 & 7) ^ (row & 7)) << 3;
                __builtin_amdgcn_global_load_lds(
                    (gas_t)(Bb + (size_t)row * K + k0 + kc),
                    (las_t)&Bs[c2 * 8], 16, 0, 0);
            }
        }
        __syncthreads();

#pragma unroll
        for (int ks = 0; ks < 2; ++ks) {
            short8 af[MI], bf[NJ];
#pragma unroll
            for (int i = 0; i < MI; ++i) {
                const int row = wm + i * 16 + fr;
                const int pos = (ks * 4 + fq) ^ (row & 7);
                af[i] = *(const short8*)&As[row * 64 + pos * 8];
            }
#pragma unroll
            for (int j = 0; j < NJ; ++j) {
                const int row = wn + j * 16 + fr;
                const int pos = (ks * 4 + fq) ^ (row & 7);
                bf[j] = *(const short8*)&Bs[row * 64 + pos * 8];
            }
#pragma unroll
            for (int i = 0; i < MI; ++i)
#pragma unroll
                for (int j = 0; j < NJ; ++j)
                    acc[i][j] = __builtin_amdgcn_mfma_f32_16x16x32_bf16(af[i], bf[j], acc[i][j], 0, 0, 0);
        }
        __syncthreads();
    }

    // Epilogue. D mapping: col = lane&15 (=fr), row = (lane>>4)*4 + reg (=fq*4+r)
    float bv[NJ];
#pragma unroll
    for (int j = 0; j < NJ; ++j) bv[j] = bias[n0 + wn + j * 16 + fr];
#pragma unroll
    for (int i = 0; i < MI; ++i) {
#pragma unroll
        for (int r = 0; r < 4; ++r) {
            const size_t row = (size_t)(m0 + wm + i * 16 + fq * 4 + r);
#pragma unroll
            for (int j = 0; j < NJ; ++j) {
                const float v = acc[i][j][r] + bv[j];
                if constexpr (sizeof(CT) == 2)
                    C[row * N + n0 + wn + j * 16 + fr] = (CT)f2b(v);
                else
                    C[row * N + n0 + wn + j * 16 + fr] = (CT)v;
            }
        }
    }
}

// ---------------------------------------------------------------------------
// R8 attention: R5's online-softmax loop (60-VGPR / 8-waves-per-SIMD class,
// best measured) + defer-max (T13) + exp2-domain fold.
// Steady-state j-step: dot(8 fma + 8 unpack) + 3 shfl + uniform branch check
// + 1 exp2 + 1 add + PV (8 unpack + 8 fma).  The rescale body (fmax, exp2,
// 9 muls) runs only when __any(p > m+8): j=0 and pathological max growth.
// The branch is wave-uniform (scalar); the body is exact for all lanes
// because it guards with fmax.  pe <= 2^8, l <= 32*2^8: ample f32 headroom.
// One block per (b,q); 256 threads; thread t: j-group g = t>>7 (j=2*jj+g),
// head h = (t&127)>>3, dims d0 = (t&7)*8 (16 B).
// qkv: bf16 [B, S, 3, H, HD]. out: bf16 [B, S, H*HD].
__global__ __launch_bounds__(256) void attn_kernel(const unsigned short* __restrict__ qkv,
                                                   const int* __restrict__ routes,
                                                   unsigned short* __restrict__ out) {
    __shared__ int   r_s[KQ];
    __shared__ float m_s[128], l_s[128];
    __shared__ float o_part[8][128];

    const int t  = threadIdx.x;           // 0..255
    const int id = blockIdx.x;
    // XCD-contiguity swizzle: same XCD (id%8) gets a contiguous bq range.
    const int bq = (id & 7) * 512 + (id >> 3);
    const int b  = bq >> 11;
    const int q  = bq & 2047;

    if (t < KQ) r_s[t] = routes[q * KQ + t];

    const int g  = t >> 7;                // j-group: 0 or 1
    const int th = t & 127;
    const int h  = th >> 3;               // head
    const int d0 = (t & 7) * 8;           // dim offset within head

    // SCALE * log2(e) folded into q so scores are directly in exp2 domain.
    float qf[8];
    {
        const short8 q8 = *(const short8*)&qkv[((size_t)bq * 3) * DIMQ + h * HDQ + d0];
#pragma unroll
        for (int e = 0; e < 8; ++e) qf[e] = b2f((unsigned short)q8[e]) * 0.18033688011112042f;
    }
    __syncthreads();

    const unsigned short* baseK = qkv + ((size_t)b * SQ * 3 + 1) * DIMQ + h * HDQ + d0;
    const unsigned short* baseV = qkv + ((size_t)b * SQ * 3 + 2) * DIMQ + h * HDQ + d0;

    float m = -1e30f, l = 0.f;
    float o[8];
#pragma unroll
    for (int e = 0; e < 8; ++e) o[e] = 0.f;

    // Prefetch pipeline: 2 slots, loads for iteration jj+2 issued during jj.
    short8 kb[2], vb[2];
#pragma unroll
    for (int i = 0; i < 2; ++i) {
        const size_t roff = (size_t)r_s[i * 2 + g] * QKV_STRIDE;
        kb[i] = *(const short8*)(baseK + roff);
        vb[i] = *(const short8*)(baseV + roff);
    }

#pragma unroll 8
    for (int jj = 0; jj < 32; ++jj) {
        const int slot = jj & 1;
        const short8 k8 = kb[slot];
        const short8 v8 = vb[slot];
        if (jj + 2 < 32) {
            const size_t roff = (size_t)r_s[(jj + 2) * 2 + g] * QKV_STRIDE;
            kb[slot] = *(const short8*)(baseK + roff);
            vb[slot] = *(const short8*)(baseV + roff);
        }
        float p = 0.f;
#pragma unroll
        for (int e = 0; e < 8; ++e) p += qf[e] * b2f((unsigned short)k8[e]);
        p += __shfl_xor(p, 1, 64);
        p += __shfl_xor(p, 2, 64);
        p += __shfl_xor(p, 4, 64);
        // Defer-max: rescale only when some lane's score jumps past m+8.
        if (__any(p > m + 8.f)) {
            const float mn = fmaxf(m, p);       // per-lane guard -> exact
            const float al = exp2f(m - mn);
            l *= al;
#pragma unroll
            for (int e = 0; e < 8; ++e) o[e] *= al;
            m = mn;
        }
        const float pe = exp2f(p - m);          // <= 2^8
        l += pe;
#pragma unroll
        for (int e = 0; e < 8; ++e) o[e] += pe * b2f((unsigned short)v8[e]);
    }

    // Merge the two j-groups (softmax state merge, exp2 domain), then store.
    if (g == 1) {
        m_s[th] = m; l_s[th] = l;
#pragma unroll
        for (int e = 0; e < 8; ++e) o_part[e][th] = o[e];
    }
    __syncthreads();
    if (g == 0) {
        const float m1 = m_s[th], l1m = l_s[th];
        const float mm = fmaxf(m, m1);
        const float a0 = exp2f(m - mm);
        const float a1 = exp2f(m1 - mm);
        const float inv = 1.0f / (l * a0 + l1m * a1);
        float oo[8];
#pragma unroll
        for (int e = 0; e < 8; ++e) oo[e] = (o[e] * a0 + o_part[e][th] * a1) * inv;
        ushort4 lo, hi;
        lo.x = f2b(oo[0]); lo.y = f2b(oo[1]); lo.z = f2b(oo[2]); lo.w = f2b(oo[3]);
        hi.x = f2b(oo[4]); hi.y = f2b(oo[5]); hi.z = f2b(oo[6]); hi.w = f2b(oo[7]);
        ushort4* dst = (ushort4*)&out[(size_t)bq * DIMQ + h * HDQ + d0];
        dst[0] = lo; dst[1] = hi;
    }
}

// ---------------------------------------------------------------------------
extern "C" void kernel_launch(void* const* d_in, const int* in_sizes, int n_in,
                              void* d_out, int out_size, void* d_ws, size_t ws_size,
                              hipStream_t stream) {
    const float* x      = (const float*)d_in[0];
    const float* w_qkv  = (const float*)d_in[1];
    const float* b_qkv  = (const float*)d_in[2];
    const float* w_out  = (const float*)d_in[3];
    const float* b_out  = (const float*)d_in[4];
    const int*   routes = (const int*)d_in[5];
    float* out = (float*)d_out;

    // ws layout (bytes): [0,24M) qkv bf16 | [24M,..) xb / attnb (aliased)
    //                    then w_qkv_bf16, w_out_bf16
    char* ws = (char*)d_ws;
    unsigned short* qkvb  = (unsigned short*)ws;                      // 24 MB
    unsigned short* xb    = (unsigned short*)(ws + 25165824);         // 8.4 MB
    unsigned short* attnb = xb;                                       // aliased
    unsigned short* wqb   = (unsigned short*)(ws + 33554432);         // 6.3 MB
    unsigned short* wob   = (unsigned short*)(ws + 39845888);         // 2.1 MB

    const int M = BQ * SQ;   // 4096
    dim3 blk(256);

    // Fused casts (x, w_qkv, w_out), float4 per thread
    {
        const int n0 = M * DIMQ / 4, n1 = 3 * DIMQ * DIMQ / 4, n2 = DIMQ * DIMQ / 4;
        cast3_f32_bf16<<<(n0 + n1 + n2 + 255) / 256, blk, 0, stream>>>(
            x, xb, n0, w_qkv, wqb, n1, w_out, wob, n2);
    }

    // 1) QKV projection -> bf16 qkv [B,S,3,H,HD]  (BK=64, 32 MFMAs/barrier)
    gemm_bf16_nt<128, 128, unsigned short><<<dim3(3 * DIMQ / 128, M / 128), blk, 0, stream>>>(
        xb, wqb, b_qkv, qkvb, M, 3 * DIMQ, DIMQ);

    // 2) Routed attention: online softmax + defer-max, register prefetch
    attn_kernel<<<BQ * SQ, blk, 0, stream>>>(qkvb, routes, attnb);

    // 3) Output projection -> fp32 final output (128x64 tiles: 512 blocks)
    gemm_bf16_nt<128, 64, float><<<dim3(DIMQ / 64, M / 128), blk, 0, stream>>>(
        attnb, wob, b_out, out, M, DIMQ, DIMQ);
}

// Round 6
// 179.567 us; speedup vs baseline: 1.1385x; 1.0359x over previous
//
#include <hip/hip_runtime.h>

// Problem constants
#define BQ   2
#define SQ   2048
#define DIMQ 1024
#define HQ   16
#define HDQ  64
#define KQ   64
#define QKV_STRIDE (3 * DIMQ)

typedef __attribute__((ext_vector_type(8))) short short8;   // 8 bf16 (4 VGPRs)
typedef __attribute__((ext_vector_type(4))) float floatx4;  // 4 fp32 acc
typedef __attribute__((ext_vector_type(2))) float floatx2;  // packed f32 pair
typedef __attribute__((ext_vector_type(4))) unsigned int uintx4;  // 4x(2 bf16)

typedef const __attribute__((address_space(1))) unsigned short* gas_t;
typedef __attribute__((address_space(3))) unsigned short* las_t;

__device__ __forceinline__ unsigned short f2b(float f) {
    union { float f; unsigned int u; } x; x.f = f;
    unsigned int r = x.u + 0x7fffu + ((x.u >> 16) & 1u);   // RNE
    return (unsigned short)(r >> 16);
}
__device__ __forceinline__ float b2f(unsigned short u) {
    union { unsigned int u; float f; } x; x.u = ((unsigned int)u) << 16;
    return x.f;
}
__device__ __forceinline__ float u2f(unsigned int u) {
    union { unsigned int u; float f; } x; x.u = u;
    return x.f;
}

// ---------------------------------------------------------------------------
// Fused fp32 -> bf16 cast over three buffers (x, w_qkv, w_out), float4 lanes.
__global__ __launch_bounds__(256) void cast3_f32_bf16(const float* __restrict__ s0, unsigned short* __restrict__ d0, int n0,
                                                      const float* __restrict__ s1, unsigned short* __restrict__ d1, int n1,
                                                      const float* __restrict__ s2, unsigned short* __restrict__ d2, int n2) {
    int i = blockIdx.x * blockDim.x + threadIdx.x;
    const float* s; unsigned short* d;
    if (i < n0)                { s = s0; d = d0; }
    else if (i < n0 + n1)      { s = s1; d = d1; i -= n0; }
    else if (i < n0 + n1 + n2) { s = s2; d = d2; i -= n0 + n1; }
    else return;
    float4 v = ((const float4*)s)[i];
    ushort4 o;
    o.x = f2b(v.x); o.y = f2b(v.y); o.z = f2b(v.z); o.w = f2b(v.w);
    ((ushort4*)d)[i] = o;
}

// ---------------------------------------------------------------------------
// C[M,N] = A[M,K] @ B[N,K]^T + bias[N]   (A,B bf16 row-major; C fp32 or bf16)
// BMxBN tile, BK=64 (32 MFMAs between barriers), 256 threads = 4 waves
// (2x2 of BM/2 x BN/2), 16x16x32 MFMA. XOR k-chunk swizzle on the global side.
template <int BM, int BN, typename CT>
__global__ __launch_bounds__(256) void gemm_bf16_nt(const unsigned short* __restrict__ A,
                                                    const unsigned short* __restrict__ B,
                                                    const float* __restrict__ bias,
                                                    CT* __restrict__ C,
                                                    int M, int N, int K) {
    constexpr int MI = BM / 32;          // 16-row mfma tiles per wave
    constexpr int NJ = BN / 32;          // 16-col mfma tiles per wave
    __shared__ unsigned short As[BM * 64];
    __shared__ unsigned short Bs[BN * 64];

    const int tid  = threadIdx.x;
    const int lane = tid & 63;
    const int wv   = tid >> 6;            // 0..3
    const int wm   = (wv >> 1) * (BM / 2);
    const int wn   = (wv & 1) * (BN / 2);
    const int fr   = lane & 15;           // fragment row (m or n)
    const int fq   = lane >> 4;           // quad -> k segment (8 elems)

    const int m0 = blockIdx.y * BM;
    const int n0 = blockIdx.x * BN;

    floatx4 acc[MI][NJ];
#pragma unroll
    for (int i = 0; i < MI; ++i)
#pragma unroll
        for (int j = 0; j < NJ; ++j) acc[i][j] = (floatx4)(0.f);

    const unsigned short* Ab = A + (size_t)m0 * K;
    const unsigned short* Bb = B + (size_t)n0 * K;

    for (int k0 = 0; k0 < K; k0 += 64) {
#pragma unroll
        for (int c = 0; c < (BM + BN) * 8; c += 256) {
            const int cc = c + tid;
            if (cc < BM * 8) {
                const int row = cc >> 3;
                const int kc  = ((cc & 7) ^ (row & 7)) << 3;
                __builtin_amdgcn_global_load_lds(
                    (gas_t)(Ab + (size_t)row * K + k0 + kc),
                    (las_t)&As[cc * 8], 16, 0, 0);
            } else {
                const int c2  = cc - BM * 8;
                const int row = c2 >> 3;
                const int kc  = ((c2 & 7) ^ (row & 7)) << 3;
                __builtin_amdgcn_global_load_lds(
                    (gas_t)(Bb + (size_t)row * K + k0 + kc),
                    (las_t)&Bs[c2 * 8], 16, 0, 0);
            }
        }
        __syncthreads();

#pragma unroll
        for (int ks = 0; ks < 2; ++ks) {
            short8 af[MI], bf[NJ];
#pragma unroll
            for (int i = 0; i < MI; ++i) {
                const int row = wm + i * 16 + fr;
                const int pos = (ks * 4 + fq) ^ (row & 7);
                af[i] = *(const short8*)&As[row * 64 + pos * 8];
            }
#pragma unroll
            for (int j = 0; j < NJ; ++j) {
                const int row = wn + j * 16 + fr;
                const int pos = (ks * 4 + fq) ^ (row & 7);
                bf[j] = *(const short8*)&Bs[row * 64 + pos * 8];
            }
#pragma unroll
            for (int i = 0; i < MI; ++i)
#pragma unroll
                for (int j = 0; j < NJ; ++j)
                    acc[i][j] = __builtin_amdgcn_mfma_f32_16x16x32_bf16(af[i], bf[j], acc[i][j], 0, 0, 0);
        }
        __syncthreads();
    }

    // Epilogue. D mapping: col = lane&15 (=fr), row = (lane>>4)*4 + reg (=fq*4+r)
    float bv[NJ];
#pragma unroll
    for (int j = 0; j < NJ; ++j) bv[j] = bias[n0 + wn + j * 16 + fr];
#pragma unroll
    for (int i = 0; i < MI; ++i) {
#pragma unroll
        for (int r = 0; r < 4; ++r) {
            const size_t row = (size_t)(m0 + wm + i * 16 + fq * 4 + r);
#pragma unroll
            for (int j = 0; j < NJ; ++j) {
                const float v = acc[i][j][r] + bv[j];
                if constexpr (sizeof(CT) == 2)
                    C[row * N + n0 + wn + j * 16 + fr] = (CT)f2b(v);
                else
                    C[row * N + n0 + wn + j * 16 + fr] = (CT)v;
            }
        }
    }
}

// ---------------------------------------------------------------------------
// R9 attention: R8 structure + hardware bf16 dot (v_dot2_f32_bf16) for QK^T
// and packed-f32 (float2 -> v_pk_fma_f32) PV accumulation.
// QK dot: 4 dot2 instructions on packed bf16 (no unpack, q stays packed).
// Scores stay in RAW units; SCALE*log2(e) is applied inside the exp2 arg,
// so defer-max threshold is 44 raw units (= 8 in exp2 domain, pe <= 2^8).
// Steady-state j-step: 1 ds_read + ~5 addr + 4 dot2 + 3 shfl + (cmp) +
// sub+mul+exp2+add + 8 unpack + 4 pk_fma  (~31 slots vs R8's ~47).
// One block per (b,q); 256 threads; thread t: j-group g = t>>7 (j=2*jj+g),
// head h = (t&127)>>3, dims d0 = (t&7)*8 (16 B).
// qkv: bf16 [B, S, 3, H, HD]. out: bf16 [B, S, H*HD].
__global__ __launch_bounds__(256) void attn_kernel(const unsigned short* __restrict__ qkv,
                                                   const int* __restrict__ routes,
                                                   unsigned short* __restrict__ out) {
    __shared__ int   r_s[KQ];
    __shared__ float m_s[128], l_s[128];
    __shared__ float o_part[8][128];

    const int t  = threadIdx.x;           // 0..255
    const int id = blockIdx.x;
    // XCD-contiguity swizzle: same XCD (id%8) gets a contiguous bq range.
    const int bq = (id & 7) * 512 + (id >> 3);
    const int b  = bq >> 11;
    const int q  = bq & 2047;

    if (t < KQ) r_s[t] = routes[q * KQ + t];

    const int g  = t >> 7;                // j-group: 0 or 1
    const int th = t & 127;
    const int h  = th >> 3;               // head
    const int d0 = (t & 7) * 8;           // dim offset within head

    // q stays PACKED bf16 (4 uints = 8 elems); scale applied in exp2 arg.
    const uintx4 qp = *(const uintx4*)&qkv[((size_t)bq * 3) * DIMQ + h * HDQ + d0];
    __syncthreads();

    const unsigned short* baseK = qkv + ((size_t)b * SQ * 3 + 1) * DIMQ + h * HDQ + d0;
    const unsigned short* baseV = qkv + ((size_t)b * SQ * 3 + 2) * DIMQ + h * HDQ + d0;

    const float C = 0.18033688011112042f;   // SCALE * log2(e)
    float m = -1e30f, l = 0.f;
    floatx2 o2[4];
#pragma unroll
    for (int i = 0; i < 4; ++i) o2[i] = (floatx2)(0.f);

    // Prefetch pipeline: 2 slots, loads for iteration jj+2 issued during jj.
    uintx4 kb[2], vb[2];
#pragma unroll
    for (int i = 0; i < 2; ++i) {
        const size_t roff = (size_t)r_s[i * 2 + g] * QKV_STRIDE;
        kb[i] = *(const uintx4*)(baseK + roff);
        vb[i] = *(const uintx4*)(baseV + roff);
    }

#pragma unroll 8
    for (int jj = 0; jj < 32; ++jj) {
        const int slot = jj & 1;
        const uintx4 k4 = kb[slot];
        const uintx4 v4 = vb[slot];
        if (jj + 2 < 32) {
            const size_t roff = (size_t)r_s[(jj + 2) * 2 + g] * QKV_STRIDE;
            kb[slot] = *(const uintx4*)(baseK + roff);
            vb[slot] = *(const uintx4*)(baseV + roff);
        }
        // QK dot: 4x v_dot2_f32_bf16 on packed bf16 pairs (no unpack).
        float p = 0.f;
#pragma unroll
        for (int i = 0; i < 4; ++i)
            asm("v_dot2_f32_bf16 %0, %1, %2, %0" : "+v"(p) : "v"(qp[i]), "v"(k4[i]));
        p += __shfl_xor(p, 1, 64);
        p += __shfl_xor(p, 2, 64);
        p += __shfl_xor(p, 4, 64);
        // Defer-max: rescale only when some lane's raw score jumps past m+44
        // (44 raw units * C = ~8 in exp2 domain -> pe <= 2^8).
        if (__any(p > m + 44.f)) {
            const float mn = fmaxf(m, p);       // per-lane guard -> exact
            const float al = exp2f((m - mn) * C);
            l *= al;
            const floatx2 al2 = { al, al };
#pragma unroll
            for (int i = 0; i < 4; ++i) o2[i] *= al2;
            m = mn;
        }
        const float pe = exp2f((p - m) * C);    // <= 2^8
        l += pe;
        // PV: unpack bf16 pair (shift + and) then packed f32 FMA.
        const floatx2 pe2 = { pe, pe };
#pragma unroll
        for (int i = 0; i < 4; ++i) {
            const unsigned int u = v4[i];
            floatx2 vv;
            vv.x = u2f(u << 16);
            vv.y = u2f(u & 0xffff0000u);
            o2[i] += pe2 * vv;
        }
    }

    // Merge the two j-groups (softmax state merge, exp2 domain), then store.
    if (g == 1) {
        m_s[th] = m; l_s[th] = l;
#pragma unroll
        for (int i = 0; i < 4; ++i) {
            o_part[2 * i][th]     = o2[i].x;
            o_part[2 * i + 1][th] = o2[i].y;
        }
    }
    __syncthreads();
    if (g == 0) {
        const float m1 = m_s[th], l1m = l_s[th];
        const float mm = fmaxf(m, m1);
        const float a0 = exp2f((m - mm) * C);
        const float a1 = exp2f((m1 - mm) * C);
        const float inv = 1.0f / (l * a0 + l1m * a1);
        float oo[8];
#pragma unroll
        for (int i = 0; i < 4; ++i) {
            oo[2 * i]     = (o2[i].x * a0 + o_part[2 * i][th] * a1) * inv;
            oo[2 * i + 1] = (o2[i].y * a0 + o_part[2 * i + 1][th] * a1) * inv;
        }
        ushort4 lo, hi;
        lo.x = f2b(oo[0]); lo.y = f2b(oo[1]); lo.z = f2b(oo[2]); lo.w = f2b(oo[3]);
        hi.x = f2b(oo[4]); hi.y = f2b(oo[5]); hi.z = f2b(oo[6]); hi.w = f2b(oo[7]);
        ushort4* dst = (ushort4*)&out[(size_t)bq * DIMQ + h * HDQ + d0];
        dst[0] = lo; dst[1] = hi;
    }
}

// ---------------------------------------------------------------------------
extern "C" void kernel_launch(void* const* d_in, const int* in_sizes, int n_in,
                              void* d_out, int out_size, void* d_ws, size_t ws_size,
                              hipStream_t stream) {
    const float* x      = (const float*)d_in[0];
    const float* w_qkv  = (const float*)d_in[1];
    const float* b_qkv  = (const float*)d_in[2];
    const float* w_out  = (const float*)d_in[3];
    const float* b_out  = (const float*)d_in[4];
    const int*   routes = (const int*)d_in[5];
    float* out = (float*)d_out;

    // ws layout (bytes): [0,24M) qkv bf16 | [24M,..) xb / attnb (aliased)
    //                    then w_qkv_bf16, w_out_bf16
    char* ws = (char*)d_ws;
    unsigned short* qkvb  = (unsigned short*)ws;                      // 24 MB
    unsigned short* xb    = (unsigned short*)(ws + 25165824);         // 8.4 MB
    unsigned short* attnb = xb;                                       // aliased
    unsigned short* wqb   = (unsigned short*)(ws + 33554432);         // 6.3 MB
    unsigned short* wob   = (unsigned short*)(ws + 39845888);         // 2.1 MB

    const int M = BQ * SQ;   // 4096
    dim3 blk(256);

    // Fused casts (x, w_qkv, w_out), float4 per thread
    {
        const int n0 = M * DIMQ / 4, n1 = 3 * DIMQ * DIMQ / 4, n2 = DIMQ * DIMQ / 4;
        cast3_f32_bf16<<<(n0 + n1 + n2 + 255) / 256, blk, 0, stream>>>(
            x, xb, n0, w_qkv, wqb, n1, w_out, wob, n2);
    }

    // 1) QKV projection -> bf16 qkv [B,S,3,H,HD]  (BK=64, 32 MFMAs/barrier)
    gemm_bf16_nt<128, 128, unsigned short><<<dim3(3 * DIMQ / 128, M / 128), blk, 0, stream>>>(
        xb, wqb, b_qkv, qkvb, M, 3 * DIMQ, DIMQ);

    // 2) Routed attention: online softmax + defer-max + hw bf16 dot
    attn_kernel<<<BQ * SQ, blk, 0, stream>>>(qkvb, routes, attnb);

    // 3) Output projection -> fp32 final output (128x64 tiles: 512 blocks)
    gemm_bf16_nt<128, 64, float><<<dim3(DIMQ / 64, M / 128), blk, 0, stream>>>(
        attnb, wob, b_out, out, M, DIMQ, DIMQ);
}